// Round 2
// 892.076 us; speedup vs baseline: 1.4990x; 1.4990x over previous
//
#include <hip/hip_runtime.h>
#include <cmath>

// RWKV7 time-mixing, B=4 L=2048 D=1024 H=16 Dh=64. Inputs/outputs fp32; internal bf16.
// convert(lora wts) -> mix -> [r,k,v (B=f32)] + lora1 -> lora2 -> prep_pack(stream) ->
// scan v6 (256 blocks = 4 row-quarters/head, DPP row reductions, reg-prefetched,
//          LDS double-buffered global_load_lds batches) -> gnorm -> out GEMM.

#define DEV __device__ __forceinline__

typedef unsigned short u16;
typedef unsigned int u32;
typedef __bf16 bf16x8 __attribute__((ext_vector_type(8)));
typedef float f32x4 __attribute__((ext_vector_type(4)));

constexpr int Bx = 4, Lx = 2048, Dx = 1024, Hx = 16, Dh = 64;
constexpr int NTOK = Bx * Lx;       // 8192
constexpr float EPS_GN = 0.00064f;
constexpr int STEP_U16 = 384;       // 768B per step: r|k|a|b|v|w (64 bf16 each)
constexpr int TB = 16;              // steps per scan batch
constexpr int NB = Lx / TB;         // 128 batches
constexpr int BATCH_U16 = TB * STEP_U16;   // 6144 u16 = 12288 B

DEV float bf2f(u16 u) { union { u32 i; float f; } c; c.i = ((u32)u) << 16; return c.f; }
DEV u16 f2bf(float f) {
    union { float f; u32 i; } c; c.f = f;
    u32 r = c.i + 0x7FFFu + ((c.i >> 16) & 1u);
    return (u16)(r >> 16);
}
DEV void unpack2(u32 u, float& a, float& b) {
    union { u32 i; float f; } c0, c1;
    c0.i = u << 16; c1.i = u & 0xFFFF0000u;
    a = c0.f; b = c1.f;
}

// DPP butterfly add: returns v + v[lane ^ mask] for masks {1,2,7,15} via pure-VALU DPP.
// 0xB1 = quad_perm[1,0,3,2] (xor1), 0x4E = quad_perm[2,3,0,1] (xor2),
// 0x141 = row_half_mirror (xor7 after quads uniform), 0x140 = row_mirror (xor15).
template <int CTRL>
DEV float dpp_add(float v) {
    int p = __builtin_amdgcn_update_dpp(0, __float_as_int(v), CTRL, 0xF, 0xF, true);
    return v + __int_as_float(p);
}

// ---------------- lora-weight f32 -> bf16 conversion (8 small tensors) ----------------
__global__ __launch_bounds__(256) void conv_kernel(
    const float* s0, const float* s1, const float* s2, const float* s3,
    const float* s4, const float* s5, const float* s6, const float* s7,
    u16* d0, u16* d1, u16* d2, u16* d3, u16* d4, u16* d5, u16* d6, u16* d7)
{
    const float* srcs[8] = {s0,s1,s2,s3,s4,s5,s6,s7};
    u16* dsts[8] = {d0,d1,d2,d3,d4,d5,d6,d7};
    const int ns[8] = {65536,65536,32768,32768,65536,65536,131072,131072};
    int t = blockIdx.y;
    int i = (blockIdx.x * 256 + threadIdx.x) * 4;
    if (i >= ns[t]) return;
    float4 v = *(const float4*)(srcs[t] + i);
    ushort4 o;
    o.x = f2bf(v.x); o.y = f2bf(v.y); o.z = f2bf(v.z); o.w = f2bf(v.w);
    *(ushort4*)(dsts[t] + i) = o;
}

// ---------------- token-shift mix ----------------
__global__ __launch_bounds__(256) void mix_kernel(
    const float* __restrict__ x,
    const float* __restrict__ mr, const float* __restrict__ mw, const float* __restrict__ mk,
    const float* __restrict__ mv, const float* __restrict__ ma, const float* __restrict__ mg,
    u16* __restrict__ XR, u16* __restrict__ XW, u16* __restrict__ XK,
    u16* __restrict__ XV, u16* __restrict__ XA, u16* __restrict__ XG)
{
    int gi = blockIdx.x * 256 + threadIdx.x;
    int n  = gi >> 8;
    int d4 = (gi & 255) << 2;
    int l  = n & (Lx - 1);
    size_t o = (size_t)n * Dx + d4;
    float4 xc = *(const float4*)(x + o);
    float4 xp = make_float4(0.f, 0.f, 0.f, 0.f);
    if (l != 0) xp = *(const float4*)(x + o - Dx);
    float dx0 = xp.x - xc.x, dx1 = xp.y - xc.y, dx2 = xp.z - xc.z, dx3 = xp.w - xc.w;
    const float* mvs[6] = {mr, mw, mk, mv, ma, mg};
    u16* dsts[6] = {XR, XW, XK, XV, XA, XG};
#pragma unroll
    for (int j = 0; j < 6; ++j) {
        float4 m = *(const float4*)(mvs[j] + d4);
        ushort4 r;
        r.x = f2bf(fmaf(dx0, m.x, xc.x));
        r.y = f2bf(fmaf(dx1, m.y, xc.y));
        r.z = f2bf(fmaf(dx2, m.z, xc.z));
        r.w = f2bf(fmaf(dx3, m.w, xc.w));
        *(ushort4*)(dsts[j] + o) = r;
    }
}

// ---------------- bf16 MFMA GEMM, C[M,N] = act(A[M,K] . B[N,K]^T + bias_f32) ----------------
// ACT: 0 none, 1 sigmoid, 2 tanh, 3 exp(-0.606531*sigmoid). BF32: B matrix is f32 (converted in staging).
template <int BN, int ACT, bool BIAS, bool F32OUT, bool BF32>
__global__ __launch_bounds__(256) void gemm_nt(
    const u16* __restrict__ A, const void* __restrict__ Bmv,
    const float* __restrict__ bias, void* __restrict__ Cv,
    int M, int N, int K)
{
    constexpr int BM = 128, BK = 32;
    constexpr int LDT = BK + 8;
    constexpr int WGM = (BN == 128) ? 2 : 4;
    constexpr int WGN = (BN == 128) ? 2 : 1;
    constexpr int WTM = BM / WGM, WTN = BN / WGN;
    constexpr int ITM = WTM / 16, ITN = WTN / 16;
    __shared__ __align__(16) u16 Asm[BM * LDT];
    __shared__ __align__(16) u16 Bsm[BN * LDT];
    const int tid = threadIdx.x;
    const int wid = tid >> 6, lane = tid & 63;
    const int q = lane >> 4, r16 = lane & 15;
    const size_t m0 = (size_t)blockIdx.x * BM;
    const size_t n0 = (size_t)blockIdx.y * BN;
    const int wm = (wid % WGM) * WTM;
    const int wn = (wid / WGM) * WTN;
    f32x4 acc[ITM][ITN];
    const f32x4 zf = {0.f, 0.f, 0.f, 0.f};
#pragma unroll
    for (int i = 0; i < ITM; ++i)
#pragma unroll
        for (int j = 0; j < ITN; ++j) acc[i][j] = zf;

    const u16* B16 = (const u16*)Bmv;
    const float* B32 = (const float*)Bmv;

    for (int k0 = 0; k0 < K; k0 += BK) {
#pragma unroll
        for (int it = 0; it < (BM * BK) / 2048; ++it) {
            int pp = tid * 8 + it * 2048;
            int row = pp >> 5, col = pp & 31;
            *(uint4*)&Asm[row * LDT + col] = *(const uint4*)(A + (m0 + row) * K + k0 + col);
        }
#pragma unroll
        for (int it = 0; it < (BN * BK + 2047) / 2048; ++it) {
            int pp = tid * 8 + it * 2048;
            if (BN * BK >= 2048 || pp < BN * BK) {
                int row = pp >> 5, col = pp & 31;
                if constexpr (BF32) {
                    float4 f0 = *(const float4*)(B32 + (n0 + row) * K + k0 + col);
                    float4 f1 = *(const float4*)(B32 + (n0 + row) * K + k0 + col + 4);
                    ushort4 o0, o1;
                    o0.x = f2bf(f0.x); o0.y = f2bf(f0.y); o0.z = f2bf(f0.z); o0.w = f2bf(f0.w);
                    o1.x = f2bf(f1.x); o1.y = f2bf(f1.y); o1.z = f2bf(f1.z); o1.w = f2bf(f1.w);
                    *(ushort4*)&Bsm[row * LDT + col] = o0;
                    *(ushort4*)&Bsm[row * LDT + col + 4] = o1;
                } else {
                    *(uint4*)&Bsm[row * LDT + col] = *(const uint4*)(B16 + (n0 + row) * K + k0 + col);
                }
            }
        }
        __syncthreads();
        bf16x8 af[ITM], bfr[ITN];
#pragma unroll
        for (int im = 0; im < ITM; ++im)
            af[im] = *(const bf16x8*)&Asm[(wm + im * 16 + r16) * LDT + q * 8];
#pragma unroll
        for (int in = 0; in < ITN; ++in)
            bfr[in] = *(const bf16x8*)&Bsm[(wn + in * 16 + r16) * LDT + q * 8];
#pragma unroll
        for (int im = 0; im < ITM; ++im)
#pragma unroll
            for (int in = 0; in < ITN; ++in)
                acc[im][in] = __builtin_amdgcn_mfma_f32_16x16x32_bf16(af[im], bfr[in], acc[im][in], 0, 0, 0);
        __syncthreads();
    }
#pragma unroll
    for (int im = 0; im < ITM; ++im) {
#pragma unroll
        for (int in = 0; in < ITN; ++in) {
#pragma unroll
            for (int e = 0; e < 4; ++e) {
                size_t row = m0 + wm + im * 16 + q * 4 + e;
                size_t col = n0 + wn + in * 16 + r16;
                float val = acc[im][in][e];
                if constexpr (BIAS) val += bias[col];
                if constexpr (ACT == 1) val = 1.f / (1.f + __expf(-val));
                else if constexpr (ACT == 2) val = tanhf(val);
                else if constexpr (ACT == 3) val = __expf(-0.606531f / (1.f + __expf(-val)));
                if constexpr (F32OUT) ((float*)Cv)[row * (size_t)N + col] = val;
                else ((u16*)Cv)[row * (size_t)N + col] = f2bf(val);
            }
        }
    }
}

// ---------------- prep + pack: kk-norm, a/b, k/v updates, emit packed stream ----------------
__global__ __launch_bounds__(256) void prep_pack_kernel(
    u16* __restrict__ Kb, u16* __restrict__ Vb,
    const u16* __restrict__ Rb, const u16* __restrict__ Wd16,
    const u16* __restrict__ ICLR, const u16* __restrict__ VVb, const float* __restrict__ vfirst,
    const float* __restrict__ k_k, const float* __restrict__ k_a,
    u16* __restrict__ stream)
{
    int g = blockIdx.x * 4 + (threadIdx.x >> 6);   // (token,head) pair: n = g>>4, h = g&15
    int lane = threadIdx.x & 63;
    int h = g & (Hx - 1);
    int n = g >> 4;
    size_t idx = (size_t)g * 64 + lane;            // == n*1024 + h*64 + lane
    int hd = h * 64 + lane;
    int l = n & (Lx - 1), b = n >> 11;
    size_t so = ((size_t)((b * 16 + h) * Lx + l)) * STEP_U16;

    float k = bf2f(Kb[idx]);
    float iclr = bf2f(ICLR[idx]);
    float kkn = k * k_k[hd];
    float s = kkn * kkn;
#pragma unroll
    for (int off = 32; off > 0; off >>= 1) s += __shfl_xor(s, off, 64);
    float nrm = fmaxf(sqrtf(s), 1e-7f);
    float kk = kkn / nrm;
    u16 knew = f2bf(k * (1.f + (iclr - 1.f) * k_a[hd]));
    float v = bf2f(Vb[idx]), vv = bf2f(VVb[idx]), vf = vfirst[idx];
    u16 vnew = f2bf(fmaf(vf - v, vv, v));
    Kb[idx] = knew;
    Vb[idx] = vnew;
    stream[so + lane]       = Rb[idx];
    stream[so + 64 + lane]  = knew;
    stream[so + 128 + lane] = f2bf(-kk);
    stream[so + 192 + lane] = f2bf(kk * iclr);
    stream[so + 256 + lane] = vnew;
    stream[so + 320 + lane] = Wd16[idx];
}

// ---------------- WKV7 scan v6 ----------------
// 256 blocks = 64 (b,h) x 4 row-quarters. 4 waves/block; wave = 4 rows x 16 lanes/row;
// lane: rowidx=lane>>4, cg=lane&15 (cols 4cg..4cg+3). S[4]/thread.
// Row reductions via DPP butterfly (xor 1,2,7,15 = quad_perm,quad_perm,half_mirror,mirror).
// Batches of 16 steps staged async via global_load_lds (double-buffered); next-step
// fragments register-prefetched so ds_read latency hides under the serial chain.
__global__ __launch_bounds__(256, 1) void scan_kernel(
    const u16* __restrict__ stream, float* __restrict__ Y)
{
    const int blk = blockIdx.x;                   // 0..255
    const int bh = blk >> 2;
    const int rq = blk & 3;
    const int tid = threadIdx.x;
    const int lane = tid & 63;
    const int w = tid >> 6;
    const int cg = lane & 15, rowidx = lane >> 4;
    const int lr = w * 4 + rowidx;                // local row 0..15
    const int row = rq * 16 + lr;                 // global row 0..63
    const size_t sbase = (size_t)bh * Lx * STEP_U16;
    const size_t ybase = (size_t)(bh >> 4) * ((size_t)Lx * Dx) + (size_t)(bh & 15) * 64;

    __shared__ __align__(16) u16 sbuf[2 * BATCH_U16];   // 24 KB
    __shared__ __align__(16) float ylds[TB * 16];       // 1 KB

    float S[4] = {0.f, 0.f, 0.f, 0.f};

    // stage batch 0 into buf 0 (wave w handles 1KB chunks 3w..3w+2)
    {
        const u16* g = stream + sbase;
#pragma unroll
        for (int c = 0; c < 3; ++c) {
            const u16* gp = g + (3 * w + c) * 512 + lane * 8;
            u16* lp = sbuf + (3 * w + c) * 512;
            __builtin_amdgcn_global_load_lds(
                (const __attribute__((address_space(1))) void*)gp,
                (__attribute__((address_space(3))) void*)lp, 16, 0, 0);
        }
    }

    for (int bt = 0; bt < NB; ++bt) {
        const int cur = bt & 1;
        __syncthreads();   // vmcnt(0): batch bt resident; ylds free from prev flush
        if (bt + 1 < NB) {
            const u16* g = stream + sbase + (size_t)(bt + 1) * BATCH_U16;
            u16* lbase = sbuf + (1 - cur) * BATCH_U16;
#pragma unroll
            for (int c = 0; c < 3; ++c) {
                const u16* gp = g + (3 * w + c) * 512 + lane * 8;
                u16* lp = lbase + (3 * w + c) * 512;
                __builtin_amdgcn_global_load_lds(
                    (const __attribute__((address_space(1))) void*)gp,
                    (__attribute__((address_space(3))) void*)lp, 16, 0, 0);
            }
        }
        const u16* bp = sbuf + cur * BATCH_U16;
        const u16* cp = bp + cg * 4;
        uint2 r2 = *(const uint2*)(cp);
        uint2 k2 = *(const uint2*)(cp + 64);
        uint2 a2 = *(const uint2*)(cp + 128);
        uint2 b2 = *(const uint2*)(cp + 192);
        uint2 w2 = *(const uint2*)(cp + 320);
        float v = bf2f(bp[256 + row]);
#pragma unroll
        for (int s = 0; s < TB; ++s) {
            uint2 nr = {0, 0}, nk = {0, 0}, na = {0, 0}, nbv = {0, 0}, nw = {0, 0};
            float nv = 0.f;
            if (s + 1 < TB) {          // compile-time under full unroll
                const u16* np = cp + (s + 1) * STEP_U16;
                nr  = *(const uint2*)(np);
                nk  = *(const uint2*)(np + 64);
                na  = *(const uint2*)(np + 128);
                nbv = *(const uint2*)(np + 192);
                nw  = *(const uint2*)(np + 320);
                nv  = bf2f(bp[(s + 1) * STEP_U16 + 256 + row]);
            }
            float rr[4], kk[4], aa[4], bb[4], ww[4];
            unpack2(r2.x, rr[0], rr[1]); unpack2(r2.y, rr[2], rr[3]);
            unpack2(k2.x, kk[0], kk[1]); unpack2(k2.y, kk[2], kk[3]);
            unpack2(a2.x, aa[0], aa[1]); unpack2(a2.y, aa[2], aa[3]);
            unpack2(b2.x, bb[0], bb[1]); unpack2(b2.y, bb[2], bb[3]);
            unpack2(w2.x, ww[0], ww[1]); unpack2(w2.y, ww[2], ww[3]);
            // sa_i = sum_j S_ij * a_j  (4 local + 16-lane DPP butterfly)
            float sa0 = S[0] * aa[0], sa1 = S[1] * aa[1];
            sa0 = fmaf(S[2], aa[2], sa0); sa1 = fmaf(S[3], aa[3], sa1);
            float sa = sa0 + sa1;
            sa = dpp_add<0xB1>(sa);    // xor 1
            sa = dpp_add<0x4E>(sa);    // xor 2
            sa = dpp_add<0x141>(sa);   // xor 7  (row_half_mirror)
            sa = dpp_add<0x140>(sa);   // xor 15 (row_mirror)
            // S_ij = S_ij*w_j + v_i*k_j + sa_i*b_j ; y_i = sum_j S_ij*r_j
            float t0 = fmaf(v, kk[0], sa * bb[0]);
            float t1 = fmaf(v, kk[1], sa * bb[1]);
            float t2 = fmaf(v, kk[2], sa * bb[2]);
            float t3 = fmaf(v, kk[3], sa * bb[3]);
            S[0] = fmaf(S[0], ww[0], t0);
            S[1] = fmaf(S[1], ww[1], t1);
            S[2] = fmaf(S[2], ww[2], t2);
            S[3] = fmaf(S[3], ww[3], t3);
            float y0 = fmaf(S[1], rr[1], S[0] * rr[0]);
            float y1 = fmaf(S[3], rr[3], S[2] * rr[2]);
            float y = y0 + y1;
            y = dpp_add<0xB1>(y);
            y = dpp_add<0x4E>(y);
            y = dpp_add<0x141>(y);
            y = dpp_add<0x140>(y);
            if (cg == 0) ylds[s * 16 + lr] = y;
            r2 = nr; k2 = nk; a2 = na; b2 = nbv; w2 = nw; v = nv;
        }
        __syncthreads();   // ylds visible; batch bt+1 loads still in flight (vmem)
        // coalesced flush: 256 threads x 1 float = 256 = 16 steps x 16 rows
        {
            int s = tid >> 4, j = tid & 15;
            Y[ybase + (size_t)(bt * TB + s) * Dx + rq * 16 + j] = ylds[s * 16 + j];
        }
    }
}

// ---------------- group-norm + rkr residual + gate (OG in-place over GATE) ----------------
__global__ __launch_bounds__(256) void gnorm_kernel(
    const float* __restrict__ Y, const u16* __restrict__ Rb, const u16* __restrict__ Kb,
    const u16* __restrict__ Vb, const float* __restrict__ r_k,
    const float* __restrict__ gnw, const float* __restrict__ gnb,
    u16* __restrict__ GATE_OG)
{
    int g = blockIdx.x * 4 + (threadIdx.x >> 6);
    int lane = threadIdx.x & 63;
    int h = g & (Hx - 1);
    size_t idx = (size_t)g * 64 + lane;
    int hd = h * 64 + lane;
    float y = Y[idx];
    float r = bf2f(Rb[idx]), k = bf2f(Kb[idx]), v = bf2f(Vb[idx]);
    float rkr = r * k * r_k[hd];
    float s1 = y, s2 = y * y, s3 = rkr;
#pragma unroll
    for (int off = 32; off > 0; off >>= 1) {
        s1 += __shfl_xor(s1, off, 64);
        s2 += __shfl_xor(s2, off, 64);
        s3 += __shfl_xor(s3, off, 64);
    }
    float mean = s1 * (1.f / 64.f);
    float var  = s2 * (1.f / 64.f) - mean * mean;
    float inv = 1.f / sqrtf(var + EPS_GN);
    float o = gnw[hd] * ((y - mean) * inv) + gnb[hd];
    o += s3 * v;
    GATE_OG[idx] = f2bf(o * bf2f(GATE_OG[idx]));
}

// ---------------- launch ----------------
extern "C" void kernel_launch(void* const* d_in, const int* in_sizes, int n_in,
                              void* d_out, int out_size, void* d_ws, size_t ws_size,
                              hipStream_t stream_)
{
    const float* x      = (const float*)d_in[0];
    const float* vfirst = (const float*)d_in[1];
    const float* x_r = (const float*)d_in[2];
    const float* x_w = (const float*)d_in[3];
    const float* x_k = (const float*)d_in[4];
    const float* x_v = (const float*)d_in[5];
    const float* x_a = (const float*)d_in[6];
    const float* x_g = (const float*)d_in[7];
    const float* k_k = (const float*)d_in[8];
    const float* k_a = (const float*)d_in[9];
    const float* r_k = (const float*)d_in[10];
    const float* Wr  = (const float*)d_in[11];
    const float* Wk  = (const float*)d_in[12];
    const float* Wv  = (const float*)d_in[13];
    const float* Wo  = (const float*)d_in[14];
    const float* gnw = (const float*)d_in[15];
    const float* gnb = (const float*)d_in[16];
    const float* wA  = (const float*)d_in[17];
    const float* wB  = (const float*)d_in[18];
    const float* wb  = (const float*)d_in[19];
    const float* vA  = (const float*)d_in[20];
    const float* vB  = (const float*)d_in[21];
    const float* vb  = (const float*)d_in[22];
    const float* aA  = (const float*)d_in[23];
    const float* aB  = (const float*)d_in[24];
    const float* ab  = (const float*)d_in[25];
    const float* gA  = (const float*)d_in[26];
    const float* gB  = (const float*)d_in[27];

    char* ws = (char*)d_ws;
    const size_t SLOT = (size_t)NTOK * Dx * 2;   // 16 MiB; 14 slots total (224 MiB, proven)
    u16* XR = (u16*)(ws + 0 * SLOT);
    u16* XW = (u16*)(ws + 1 * SLOT);
    u16* XK = (u16*)(ws + 2 * SLOT);
    u16* XV = (u16*)(ws + 3 * SLOT);
    u16* XA = (u16*)(ws + 4 * SLOT);
    u16* XG = (u16*)(ws + 5 * SLOT);
    u16* STREAM = (u16*)(ws + 0 * SLOT);         // 96MB, overwrites XR..XG after consumption
    u16* Rbuf = (u16*)(ws + 6 * SLOT);
    u16* Kbuf = (u16*)(ws + 7 * SLOT);
    u16* Vbuf = (u16*)(ws + 8 * SLOT);
    u16* HW = (u16*)(ws + 9 * SLOT);             // lora hiddens (4.7MB)
    u16* HA = HW + (size_t)NTOK * 64;
    u16* HV = HA + (size_t)NTOK * 64;
    u16* HG = HV + (size_t)NTOK * 32;
    u16* SW = (u16*)(ws + 9 * SLOT + 8 * 1024 * 1024);  // small bf16 weights (1.2MB)
    u16* wAB = SW;
    u16* wBB = wAB + 65536;
    u16* vAB = wBB + 65536;
    u16* vBB = vAB + 32768;
    u16* aAB = vBB + 32768;
    u16* aBB = aAB + 65536;
    u16* gAB = aBB + 65536;
    u16* gBB = gAB + 131072;
    u16* Wdec16 = (u16*)(ws + 10 * SLOT);        // bf16 decay; dead after prep_pack
    u16* ICLR   = (u16*)(ws + 11 * SLOT);        // dead after prep_pack
    u16* VVb    = (u16*)(ws + 12 * SLOT);        // dead after prep_pack
    float* Yb   = (float*)(ws + 10 * SLOT);      // fp32, slots 10-11 (aliases Wdec16/ICLR, ordered)
    u16* GATE   = (u16*)(ws + 13 * SLOT);        // gnorm writes OG in-place

    dim3 blk(256);
    conv_kernel<<<dim3(128, 8), blk, 0, stream_>>>(wA, wB, vA, vB, aA, aB, gA, gB,
                                                   wAB, wBB, vAB, vBB, aAB, aBB, gAB, gBB);
    mix_kernel<<<(NTOK * Dx / 4) / 256, blk, 0, stream_>>>(x, x_r, x_w, x_k, x_v, x_a, x_g,
                                                           XR, XW, XK, XV, XA, XG);
    // big projections (B = f32 weights, converted in staging)
    gemm_nt<128, 0, false, false, true><<<dim3(64, 8), blk, 0, stream_>>>(XR, Wr, nullptr, Rbuf, NTOK, 1024, 1024);
    gemm_nt<128, 0, false, false, true><<<dim3(64, 8), blk, 0, stream_>>>(XK, Wk, nullptr, Kbuf, NTOK, 1024, 1024);
    gemm_nt<128, 0, false, false, true><<<dim3(64, 8), blk, 0, stream_>>>(XV, Wv, nullptr, Vbuf, NTOK, 1024, 1024);
    // lora stage 1
    gemm_nt<64, 2, false, false, false><<<dim3(64, 1), blk, 0, stream_>>>(XW, wAB, nullptr, HW, NTOK, 64, 1024);
    gemm_nt<64, 0, false, false, false><<<dim3(64, 1), blk, 0, stream_>>>(XA, aAB, nullptr, HA, NTOK, 64, 1024);
    gemm_nt<32, 0, false, false, false><<<dim3(64, 1), blk, 0, stream_>>>(XV, vAB, nullptr, HV, NTOK, 32, 1024);
    gemm_nt<128, 1, false, false, false><<<dim3(64, 1), blk, 0, stream_>>>(XG, gAB, nullptr, HG, NTOK, 128, 1024);
    // lora stage 2
    gemm_nt<128, 3, true,  false, false><<<dim3(64, 8), blk, 0, stream_>>>(HW, wBB, wb, Wdec16, NTOK, 1024, 64);
    gemm_nt<128, 1, true,  false, false><<<dim3(64, 8), blk, 0, stream_>>>(HA, aBB, ab, ICLR, NTOK, 1024, 64);
    gemm_nt<128, 1, true,  false, false><<<dim3(64, 8), blk, 0, stream_>>>(HV, vBB, vb, VVb, NTOK, 1024, 32);
    gemm_nt<128, 0, false, false, false><<<dim3(64, 8), blk, 0, stream_>>>(HG, gBB, nullptr, GATE, NTOK, 1024, 128);

    prep_pack_kernel<<<(NTOK * Hx) / 4, blk, 0, stream_>>>(Kbuf, Vbuf, Rbuf, Wdec16, ICLR, VVb,
                                                           vfirst, k_k, k_a, STREAM);
    scan_kernel<<<256, blk, 0, stream_>>>(STREAM, Yb);
    gnorm_kernel<<<(NTOK * Hx) / 4, blk, 0, stream_>>>(Yb, Rbuf, Kbuf, Vbuf, r_k, gnw, gnb, GATE);
    gemm_nt<128, 0, false, true, true><<<dim3(64, 8), blk, 0, stream_>>>(GATE, Wo, nullptr, d_out, NTOK, 1024, 1024);
}